// Round 4
// baseline (187.544 us; speedup 1.0000x reference)
//
#include <hip/hip_runtime.h>
#include <math.h>

#define N_NODES 4096
#define DIM 256
#define HEADS 4
#define HDIM 64
#define NEDGE 131072
#define MAXNBR 256
#define MASK_WORDS 128   // 4096 / 32

typedef __attribute__((ext_vector_type(8))) short short8;
typedef __attribute__((ext_vector_type(4))) float float4v;

__device__ inline unsigned short f2b(float f) {   // fp32 -> bf16 RNE
    unsigned u = __float_as_uint(f);
    unsigned r = u + 0x7fffu + ((u >> 16) & 1u);
    return (unsigned short)(r >> 16);
}
__device__ inline float b2f(unsigned short s) { return __uint_as_float(((unsigned)s) << 16); }
__device__ inline float bl(unsigned u) { return __uint_as_float(u << 16); }        // low bf16 of packed word
__device__ inline float bh(unsigned u) { return __uint_as_float(u & 0xffff0000u); }// high bf16

__device__ inline uint4 pack8(float4 a, float4 b) {
    uint4 w;
    w.x = (unsigned)f2b(a.x) | ((unsigned)f2b(a.y) << 16);
    w.y = (unsigned)f2b(a.z) | ((unsigned)f2b(a.w) << 16);
    w.z = (unsigned)f2b(b.x) | ((unsigned)f2b(b.y) << 16);
    w.w = (unsigned)f2b(b.z) | ((unsigned)f2b(b.w) << 16);
    return w;
}

// ---------------- fp32 -> bf16 conversion ----------------
__global__ void f32_to_bf16_kernel(const float* __restrict__ src,
                                   unsigned short* __restrict__ dst, int n) {
    int t = (blockIdx.x * blockDim.x + threadIdx.x) * 4;
    if (t >= n) return;
    float4 v = *(const float4*)&src[t];
    ushort4 o;
    o.x = f2b(v.x); o.y = f2b(v.y); o.z = f2b(v.z); o.w = f2b(v.w);
    *(ushort4*)&dst[t] = o;
}

// ---------------- Wc = W_p @ W_out (fused out_proj+proj), bc = W_p@b_out + b_p ----
__global__ __launch_bounds__(256)
void wc_kernel(const float* __restrict__ wp, const float* __restrict__ wout,
               const float* __restrict__ bout, const float* __restrict__ bp,
               unsigned short* __restrict__ wc, float* __restrict__ bc) {
    const int j = blockIdx.x * 16 + threadIdx.x;
    const int i = blockIdx.y * 16 + threadIdx.y;
    float acc = 0.f;
#pragma unroll 4
    for (int k = 0; k < 256; ++k)
        acc = fmaf(wp[i * 256 + k], wout[k * 256 + j], acc);
    wc[i * 256 + j] = f2b(acc);
    if (blockIdx.x == 0 && blockIdx.y == 0) {
        int t = threadIdx.y * 16 + threadIdx.x;
        float a = bp[t];
#pragma unroll 4
        for (int k = 0; k < 256; ++k)
            a = fmaf(wp[t * 256 + k], bout[k], a);
        bc[t] = a;
    }
}

// ---------------- mask / CSR construction ----------------
__global__ void build_mask_kernel(const int* __restrict__ eidx, unsigned int* __restrict__ mask) {
    int t = blockIdx.x * blockDim.x + threadIdx.x;
    if (t < NEDGE) {
        int s = eidx[t];
        int d = eidx[NEDGE + t];
        atomicOr(&mask[s * MASK_WORDS + (d >> 5)], 1u << (d & 31));
        atomicOr(&mask[d * MASK_WORDS + (s >> 5)], 1u << (s & 31));
    } else if (t < NEDGE + N_NODES) {
        int i = t - NEDGE;
        atomicOr(&mask[i * MASK_WORDS + (i >> 5)], 1u << (i & 31));
    }
}

// wave-per-row CSR extraction: lane handles 2 words, prefix-scan offsets
__global__ __launch_bounds__(256)
void extract_csr_kernel(const unsigned int* __restrict__ mask,
                        int* __restrict__ nnz, int* __restrict__ cols) {
    const int wave = threadIdx.x >> 6;
    const int lane = threadIdx.x & 63;
    const int i = blockIdx.x * 4 + wave;
    const unsigned int* row = mask + (size_t)i * MASK_WORDS;
    unsigned w0 = row[lane * 2];
    unsigned w1 = row[lane * 2 + 1];
    int cnt = __popc(w0) + __popc(w1);
    int incl = cnt;
#pragma unroll
    for (int off = 1; off < 64; off <<= 1) {
        int v = __shfl_up(incl, off, 64);
        if (lane >= off) incl += v;
    }
    int c = incl - cnt;
    int total = __shfl(incl, 63, 64);
    while (w0) {
        int b = __ffs(w0) - 1;
        if (c < MAXNBR) cols[(size_t)i * MAXNBR + c] = lane * 64 + b;
        ++c; w0 &= w0 - 1u;
    }
    while (w1) {
        int b = __ffs(w1) - 1;
        if (c < MAXNBR) cols[(size_t)i * MAXNBR + c] = lane * 64 + 32 + b;
        ++c; w1 &= w1 - 1u;
    }
    if (lane == 0) nnz[i] = total > MAXNBR ? MAXNBR : total;
}

// ---------------- bf16 MFMA GEMM:  C[M][Nc] = A[M][K] x B[Nc][K]^T + bias (+resid) ----
// BM=BN=128, BK=64, 256 threads = 4 waves (2x2 of 64x64), mfma_f32_16x16x32_bf16.
// A may be fp32 (converted during LDS staging). XOR-swizzled LDS tiles.
template <bool A_F32, bool OUT_BF16>
__global__ __launch_bounds__(256)
void mfma_gemm_bt(const void* __restrict__ Ain, const unsigned short* __restrict__ B,
                  const float* __restrict__ bias, const float* __restrict__ resid,
                  void* __restrict__ Cout, int M, int Nc, int K) {
    __shared__ unsigned short As[128 * 64];
    __shared__ unsigned short Bs[128 * 64];
    const int tid  = threadIdx.x;
    const int lane = tid & 63;
    const int wave = tid >> 6;
    const int wm = wave & 1;
    const int wn = wave >> 1;
    const int brow = blockIdx.y * 128;
    const int bcol = blockIdx.x * 128;

    float4v acc[16];
#pragma unroll
    for (int t = 0; t < 16; ++t) acc[t] = (float4v){0.f, 0.f, 0.f, 0.f};

    const int quad = lane >> 4;
    const int l16  = lane & 15;

    for (int k0 = 0; k0 < K; k0 += 64) {
        __syncthreads();
#pragma unroll
        for (int it = 0; it < 4; ++it) {
            int c = it * 256 + tid;
            int row = c >> 3;
            int col = c & 7;
            int sw  = col ^ (row & 7);
            uint4 va;
            if (A_F32) {
                const float* Af = (const float*)Ain;
                float4 a0 = *(const float4*)&Af[(size_t)(brow + row) * K + k0 + col * 8];
                float4 a1 = *(const float4*)&Af[(size_t)(brow + row) * K + k0 + col * 8 + 4];
                va = pack8(a0, a1);
            } else {
                va = *(const uint4*)&((const unsigned short*)Ain)[(size_t)(brow + row) * K + k0 + col * 8];
            }
            uint4 vb = *(const uint4*)&B[(size_t)(bcol + row) * K + k0 + col * 8];
            *(uint4*)&As[row * 64 + sw * 8] = va;
            *(uint4*)&Bs[row * 64 + sw * 8] = vb;
        }
        __syncthreads();
#pragma unroll
        for (int kk = 0; kk < 2; ++kk) {
            short8 af[4], bf[4];
#pragma unroll
            for (int mt = 0; mt < 4; ++mt) {
                int row = wm * 64 + mt * 16 + l16;
                int sw = (kk * 4 + quad) ^ (row & 7);
                af[mt] = *(const short8*)&As[row * 64 + sw * 8];
            }
#pragma unroll
            for (int nt = 0; nt < 4; ++nt) {
                int row = wn * 64 + nt * 16 + l16;
                int sw = (kk * 4 + quad) ^ (row & 7);
                bf[nt] = *(const short8*)&Bs[row * 64 + sw * 8];
            }
#pragma unroll
            for (int mt = 0; mt < 4; ++mt)
#pragma unroll
                for (int nt = 0; nt < 4; ++nt)
                    acc[mt * 4 + nt] = __builtin_amdgcn_mfma_f32_16x16x32_bf16(
                        af[mt], bf[nt], acc[mt * 4 + nt], 0, 0, 0);
        }
    }

    // epilogue: D[row = quad*4+reg][col = l16]
#pragma unroll
    for (int mt = 0; mt < 4; ++mt) {
#pragma unroll
        for (int nt = 0; nt < 4; ++nt) {
            int colg = bcol + wn * 64 + nt * 16 + l16;
            float bsv = bias[colg];
#pragma unroll
            for (int reg = 0; reg < 4; ++reg) {
                int rowg = brow + wm * 64 + mt * 16 + quad * 4 + reg;
                float v = acc[mt * 4 + nt][reg] + bsv;
                if (resid) v += resid[(size_t)rowg * Nc + colg];
                if (OUT_BF16)
                    ((unsigned short*)Cout)[(size_t)rowg * Nc + colg] = f2b(v);
                else
                    ((float*)Cout)[(size_t)rowg * Nc + colg] = v;
            }
        }
    }
}

// ---------------- sparse masked attention (bf16 qkv) ----------------
// Block (256 thr) per query row i; wave = head. qkv layout [N][768] bf16.
__global__ __launch_bounds__(256)
void attn_sparse_kernel(const unsigned short* __restrict__ qkv, const int* __restrict__ cols,
                        const int* __restrict__ nnz, unsigned short* __restrict__ ctx) {
    __shared__ float q_s[HEADS][HDIM];
    __shared__ float sc[HEADS][MAXNBR];
    __shared__ int cols_s[MAXNBR];

    const int wave = threadIdx.x >> 6;   // head
    const int lane = threadIdx.x & 63;
    const int i = blockIdx.x;
    const int h = wave;

    q_s[wave][lane] = b2f(qkv[(size_t)i * 768 + h * HDIM + lane]);
    cols_s[threadIdx.x] = cols[(size_t)i * MAXNBR + threadIdx.x];
    int count = nnz[i];
    if (count > MAXNBR) count = MAXNBR;
    __syncthreads();

    // phase 1: scores (lane t handles neighbors t, t+64, ...)
    float m_local = -1e30f;
    float sv[4];
#pragma unroll
    for (int r = 0; r < 4; ++r) {
        int t = lane + r * 64;
        float s = -1e30f;
        if (t < count) {
            int j = cols_s[t];
            const unsigned short* kp = qkv + (size_t)j * 768 + DIM + h * HDIM;
            float a = 0.f;
#pragma unroll
            for (int d = 0; d < HDIM; d += 16) {
                uint4 kv0 = *(const uint4*)&kp[d];
                uint4 kv1 = *(const uint4*)&kp[d + 8];
                float4 q0 = *(const float4*)&q_s[wave][d];
                float4 q1 = *(const float4*)&q_s[wave][d + 4];
                float4 q2 = *(const float4*)&q_s[wave][d + 8];
                float4 q3 = *(const float4*)&q_s[wave][d + 12];
                a += q0.x * bl(kv0.x) + q0.y * bh(kv0.x)
                   + q0.z * bl(kv0.y) + q0.w * bh(kv0.y)
                   + q1.x * bl(kv0.z) + q1.y * bh(kv0.z)
                   + q1.z * bl(kv0.w) + q1.w * bh(kv0.w)
                   + q2.x * bl(kv1.x) + q2.y * bh(kv1.x)
                   + q2.z * bl(kv1.y) + q2.w * bh(kv1.y)
                   + q3.x * bl(kv1.z) + q3.y * bh(kv1.z)
                   + q3.z * bl(kv1.w) + q3.w * bh(kv1.w);
            }
            s = a * 0.125f;   // 1/sqrt(64)
        }
        sv[r] = s;
        m_local = fmaxf(m_local, s);
    }
#pragma unroll
    for (int off = 32; off > 0; off >>= 1)
        m_local = fmaxf(m_local, __shfl_xor(m_local, off, 64));

    float sum_local = 0.f;
#pragma unroll
    for (int r = 0; r < 4; ++r) {
        int t = lane + r * 64;
        float e = (t < count) ? expf(sv[r] - m_local) : 0.f;
        sum_local += e;
        sc[wave][t] = e;
    }
#pragma unroll
    for (int off = 32; off > 0; off >>= 1)
        sum_local += __shfl_xor(sum_local, off, 64);
    float inv = 1.0f / sum_local;
    __syncthreads();

    // phase 2: lane = (neighbor octet ng, dim octet dg); 16B V loads, 8 nbrs/step/group,
    // two independent groups in flight per iteration.
    const int ng = lane >> 3;       // 0..7
    const int dg = lane & 7;        // dims dg*8 .. dg*8+7
    const unsigned short* vB = qkv + 2 * DIM + h * HDIM + dg * 8;
    float a0 = 0.f, a1 = 0.f, a2 = 0.f, a3 = 0.f, a4 = 0.f, a5 = 0.f, a6 = 0.f, a7 = 0.f;
    for (int t0 = 0; t0 < count; t0 += 16) {
        int tA = t0 + ng;
        int tB = t0 + 8 + ng;
        int jA = cols_s[min(tA, count - 1)];
        int jB = cols_s[min(tB, count - 1)];
        float pA = (tA < count) ? sc[wave][tA] : 0.f;
        float pB = (tB < count) ? sc[wave][tB] : 0.f;
        uint4 vA = *(const uint4*)&vB[(size_t)jA * 768];
        uint4 vCk = *(const uint4*)&vB[(size_t)jB * 768];
        a0 += pA * bl(vA.x); a1 += pA * bh(vA.x);
        a2 += pA * bl(vA.y); a3 += pA * bh(vA.y);
        a4 += pA * bl(vA.z); a5 += pA * bh(vA.z);
        a6 += pA * bl(vA.w); a7 += pA * bh(vA.w);
        a0 += pB * bl(vCk.x); a1 += pB * bh(vCk.x);
        a2 += pB * bl(vCk.y); a3 += pB * bh(vCk.y);
        a4 += pB * bl(vCk.z); a5 += pB * bh(vCk.z);
        a6 += pB * bl(vCk.w); a7 += pB * bh(vCk.w);
    }
    // reduce across the 8 neighbor-groups (lane bits 3,4,5)
#pragma unroll
    for (int off = 8; off <= 32; off <<= 1) {
        a0 += __shfl_xor(a0, off, 64); a1 += __shfl_xor(a1, off, 64);
        a2 += __shfl_xor(a2, off, 64); a3 += __shfl_xor(a3, off, 64);
        a4 += __shfl_xor(a4, off, 64); a5 += __shfl_xor(a5, off, 64);
        a6 += __shfl_xor(a6, off, 64); a7 += __shfl_xor(a7, off, 64);
    }
    if (ng == 0) {
        uint4 w;
        w.x = (unsigned)f2b(a0 * inv) | ((unsigned)f2b(a1 * inv) << 16);
        w.y = (unsigned)f2b(a2 * inv) | ((unsigned)f2b(a3 * inv) << 16);
        w.z = (unsigned)f2b(a4 * inv) | ((unsigned)f2b(a5 * inv) << 16);
        w.w = (unsigned)f2b(a6 * inv) | ((unsigned)f2b(a7 * inv) << 16);
        *(uint4*)&ctx[(size_t)i * DIM + h * HDIM + dg * 8] = w;
    }
}

// ---------------- LayerNorm ----------------
__global__ __launch_bounds__(256)
void ln_kernel(const float* __restrict__ y, const float* __restrict__ gamma,
               const float* __restrict__ beta, float* __restrict__ out) {
    const int wave = threadIdx.x >> 6;
    const int lane = threadIdx.x & 63;
    const int i = blockIdx.x * 4 + wave;
    float4 v = ((const float4*)(y + (size_t)i * DIM))[lane];
    float s = v.x + v.y + v.z + v.w;
    float ss = v.x * v.x + v.y * v.y + v.z * v.z + v.w * v.w;
#pragma unroll
    for (int off = 32; off > 0; off >>= 1) {
        s += __shfl_xor(s, off, 64);
        ss += __shfl_xor(ss, off, 64);
    }
    float mean = s * (1.f / 256.f);
    float var = ss * (1.f / 256.f) - mean * mean;
    float rstd = rsqrtf(var + 1e-5f);
    float4 g = ((const float4*)gamma)[lane];
    float4 b = ((const float4*)beta)[lane];
    float4 o;
    o.x = (v.x - mean) * rstd * g.x + b.x;
    o.y = (v.y - mean) * rstd * g.y + b.y;
    o.z = (v.z - mean) * rstd * g.z + b.z;
    o.w = (v.w - mean) * rstd * g.w + b.w;
    ((float4*)(out + (size_t)i * DIM))[lane] = o;
}

// ---------------- launch ----------------
extern "C" void kernel_launch(void* const* d_in, const int* in_sizes, int n_in,
                              void* d_out, int out_size, void* d_ws, size_t ws_size,
                              hipStream_t stream) {
    const float* x      = (const float*)d_in[0];
    const int*   eidx   = (const int*)d_in[1];
    const float* w_in   = (const float*)d_in[2];
    const float* b_in   = (const float*)d_in[3];
    const float* w_out  = (const float*)d_in[4];
    const float* b_out  = (const float*)d_in[5];
    const float* w_p    = (const float*)d_in[6];
    const float* b_p    = (const float*)d_in[7];
    const float* gamma  = (const float*)d_in[8];
    const float* beta   = (const float*)d_in[9];
    float* out = (float*)d_out;

    char* ws = (char*)d_ws;
    unsigned int*   mask    = (unsigned int*)(ws + 0);            // 2 MB
    int*            nnz     = (int*)(ws + 2097152);               // 16 KB
    int*            cols    = (int*)(ws + 2113536);               // 4 MB
    unsigned short* qkv_bf  = (unsigned short*)(ws + 6307840);    // 6 MB
    unsigned short* ctx_bf  = (unsigned short*)(ws + 12599296);   // 2 MB
    float*          ybuf    = (float*)(ws + 14696448);            // 4 MB
    unsigned short* w_in_bf = (unsigned short*)(ws + 18890752);   // 384 KB
    unsigned short* wc_bf   = (unsigned short*)(ws + 19283968);   // 128 KB
    float*          bc      = (float*)(ws + 19415040);            // 1 KB

    // w_in -> bf16
    f32_to_bf16_kernel<<<(768 * DIM / 4 + 255) / 256, 256, 0, stream>>>(w_in, w_in_bf, 768 * DIM);
    // mask zero (capture-safe async memset) + build + CSR
    hipMemsetAsync(mask, 0, N_NODES * MASK_WORDS * 4, stream);
    {
        int total = NEDGE + N_NODES;
        build_mask_kernel<<<(total + 255) / 256, 256, 0, stream>>>(eidx, mask);
        extract_csr_kernel<<<N_NODES / 4, 256, 0, stream>>>(mask, nnz, cols);
    }
    // Wc = W_p @ W_out (bf16), bc = W_p@b_out + b_p
    {
        dim3 grid(16, 16), blk(16, 16);
        wc_kernel<<<grid, blk, 0, stream>>>(w_p, w_out, b_out, b_p, wc_bf, bc);
    }
    // qkv = x @ w_in^T + b_in  -> bf16 [4096 x 768]  (A is fp32, converted in staging)
    {
        dim3 grid(768 / 128, N_NODES / 128);
        mfma_gemm_bt<true, true><<<grid, 256, 0, stream>>>(x, w_in_bf, b_in, nullptr,
                                                           qkv_bf, N_NODES, 768, DIM);
    }
    // sparse attention -> ctx bf16 [4096 x 256]
    attn_sparse_kernel<<<N_NODES, 256, 0, stream>>>(qkv_bf, cols, nnz, ctx_bf);
    // y = ctx @ Wc^T + bc + x -> fp32
    {
        dim3 grid(DIM / 128, N_NODES / 128);
        mfma_gemm_bt<false, false><<<grid, 256, 0, stream>>>(ctx_bf, wc_bf, bc, x,
                                                             ybuf, N_NODES, DIM, DIM);
    }
    // LayerNorm -> out
    ln_kernel<<<N_NODES / 4, 256, 0, stream>>>(ybuf, gamma, beta, out);
}